// Round 7
// baseline (718.356 us; speedup 1.0000x reference)
//
#include <hip/hip_runtime.h>

#define B_ALL 4096
#define NWIN  64
#define NTOK  49
#define DIMC  128
#define NH    4
#define HD    32
#define SCALE 0.17677669529663687f  // 32^-0.5

typedef __attribute__((ext_vector_type(8))) __bf16 bf16x8;
typedef __attribute__((ext_vector_type(4))) float f32x4;
typedef __attribute__((ext_vector_type(4))) unsigned int u32x4;

#define MFMA __builtin_amdgcn_mfma_f32_16x16x32_bf16

// ws layout (bytes):
//   [0,       98304)   qw_hi (384*128 bf16) ; [98304,196608) qw_lo
//   [196608, 229376)   pw_hi (128*128 bf16) ; [229376,262144) pw_lo
//   [262144, 4456448)  bmF   (64*4*64*64 f32, [wi][h][i][j], pad = -1e9)

__global__ void wpack_k(const float* __restrict__ qkv_w, const float* __restrict__ proj_w,
                        __bf16* __restrict__ dst) {
  int idx = blockIdx.x * 256 + threadIdx.x;       // 65536 total
  float w;
  __bf16 *hi, *lo;
  if (idx < 49152) { w = qkv_w[idx]; hi = dst; lo = dst + 49152; }
  else { idx -= 49152; w = proj_w[idx]; hi = dst + 98304; lo = dst + 98304 + 16384; }
  __bf16 h = (__bf16)w;
  hi[idx] = h;
  lo[idx] = (__bf16)(w - (float)h);
}

__global__ void bmf_k(const float* __restrict__ mask, const float* __restrict__ bias_table,
                      const int* __restrict__ rel_index, float* __restrict__ bmF) {
  int idx = blockIdx.x * 256 + threadIdx.x;       // 64*4*64*64 = 1048576 (exact)
  int j  = idx & 63;
  int i  = (idx >> 6) & 63;
  int h  = (idx >> 12) & 3;
  int wi = idx >> 14;
  float v = -1e9f;
  if (i < NTOK && j < NTOK)
    v = bias_table[rel_index[i * NTOK + j] * NH + h] + mask[wi * (NTOK * NTOK) + i * NTOK + j];
  bmF[idx] = v;
}

__device__ __forceinline__ unsigned int packsplit(float f) {
  union { __bf16 b; unsigned short u; } H, L;
  H.b = (__bf16)f;
  L.b = (__bf16)(f - (float)H.b);
  return ((unsigned int)H.u << 16) | L.u;
}

__device__ __forceinline__ void unpack_pair(const unsigned int* sp, bf16x8& hi, bf16x8& lo) {
  union { u32x4 q[2]; unsigned int r[8]; } t;
  t.q[0] = *(const u32x4*)sp;
  t.q[1] = *(const u32x4*)(sp + 4);
  union { bf16x8 v; unsigned short u[8]; } H, L;
#pragma unroll
  for (int e = 0; e < 8; ++e) {
    H.u[e] = (unsigned short)(t.r[e] >> 16);
    L.u[e] = (unsigned short)(t.r[e] & 0xffffu);
  }
  hi = H.v; lo = L.v;
}

// One block per window. 4 waves. Wave w owns token-rows [16w,16w+16).
// LDS (u32 units): Q[64][36] K[64][36] VT[32][68] P[64][68] AO[64][132] = 78336 B.
__global__ __launch_bounds__(256, 2)
void fused_k(const float* __restrict__ x,
             const __bf16* __restrict__ qwh, const __bf16* __restrict__ qwl,
             const float* __restrict__ qkv_b,
             const __bf16* __restrict__ pwh, const __bf16* __restrict__ pwl,
             const float* __restrict__ proj_b,
             const float* __restrict__ bmF, float* __restrict__ out) {
  __shared__ unsigned int smem[19584];
  unsigned int* Qs = smem;           // [64][36] packed(hi,lo) bf16, rows=i, cols=d(0..31)+pad
  unsigned int* Ks = smem + 2304;    // [64][36]
  unsigned int* VT = smem + 4608;    // [32][68] rows=d, cols=j(0..63)+pad
  unsigned int* Ps = smem + 6784;    // [64][68] rows=i, cols=j
  unsigned int* AO = smem + 11136;   // [64][132] rows=i, cols=c(0..127)+pad

  const int tid  = threadIdx.x;
  const int lane = tid & 63, w = tid >> 6;
  const int lrow = lane & 15, G = lane >> 4;
  const int b = blockIdx.x, wi = b & (NWIN - 1);

  // ---- x A-frags: rows 16w+lrow, k = ks*32 + 8G..+8, hi/lo. Pad rows -> 0.
  bf16x8 xh[4], xl[4];
  {
    int row = 16 * w + lrow;
    const float* xr = x + ((size_t)b * NTOK + (row < NTOK ? row : 0)) * DIMC;
#pragma unroll
    for (int ks = 0; ks < 4; ++ks) {
      float4 a = *(const float4*)(xr + ks * 32 + 8 * G);
      float4 c = *(const float4*)(xr + ks * 32 + 8 * G + 4);
      float f[8] = {a.x, a.y, a.z, a.w, c.x, c.y, c.z, c.w};
      union { bf16x8 v; __bf16 e[8]; } H, L;
#pragma unroll
      for (int e2 = 0; e2 < 8; ++e2) {
        float fv = (row < NTOK) ? f[e2] : 0.f;
        __bf16 hh = (__bf16)fv;
        H.e[e2] = hh;
        L.e[e2] = (__bf16)(fv - (float)hh);
      }
      xh[ks] = H.v; xl[ks] = L.v;
    }
  }

#pragma unroll 1
  for (int h = 0; h < NH; ++h) {
    // ======== phase 1: C = x @ Wslice^T for head h (Q|K|V cols) ========
    f32x4 acc[6];
#pragma unroll
    for (int nt = 0; nt < 6; ++nt) acc[nt] = (f32x4){0.f, 0.f, 0.f, 0.f};
#pragma unroll
    for (int ks = 0; ks < 4; ++ks) {
#pragma unroll
      for (int nt = 0; nt < 6; ++nt) {
        int seg  = nt >> 1;
        int wrow = seg * 128 + h * 32 + (nt & 1) * 16 + lrow;
        bf16x8 bh = *(const bf16x8*)(qwh + (size_t)wrow * DIMC + ks * 32 + 8 * G);
        bf16x8 bl = *(const bf16x8*)(qwl + (size_t)wrow * DIMC + ks * 32 + 8 * G);
        acc[nt] = MFMA(xh[ks], bh, acc[nt], 0, 0, 0);
        acc[nt] = MFMA(xh[ks], bl, acc[nt], 0, 0, 0);
        acc[nt] = MFMA(xl[ks], bh, acc[nt], 0, 0, 0);
      }
    }
    // epilogue: C rows i = 16w+4G+r (pad rows are exact zeros via x-pad)
#pragma unroll
    for (int nt = 0; nt < 6; ++nt) {
      int seg  = nt >> 1;
      int coln = seg * 128 + h * 32 + (nt & 1) * 16 + lrow;
      float bias = qkv_b[coln];
      if (seg == 0) {
#pragma unroll
        for (int r = 0; r < 4; ++r)
          Qs[(16 * w + 4 * G + r) * 36 + (nt & 1) * 16 + lrow] =
              packsplit((acc[nt][r] + bias) * SCALE);
      } else if (seg == 1) {
#pragma unroll
        for (int r = 0; r < 4; ++r)
          Ks[(16 * w + 4 * G + r) * 36 + (nt & 1) * 16 + lrow] =
              packsplit(acc[nt][r] + bias);
      } else {
        u32x4 pk;
#pragma unroll
        for (int r = 0; r < 4; ++r) pk[r] = packsplit(acc[nt][r] + bias);
        // VT[d][j]: d = (nt&1)*16+lrow, j = 16w+4G..+4 (b128, aligned)
        *(u32x4*)&VT[((nt & 1) * 16 + lrow) * 68 + 16 * w + 4 * G] = pk;
      }
    }
    __syncthreads();

    // ======== phase 2: attention head h; wave w = i-tile w ========
    // S^T[j][i] = sum_d K[j][d] Q[i][d]  -> tiles (mt=j-tile, nt=w)
    f32x4 sa[4];
#pragma unroll
    for (int mt = 0; mt < 4; ++mt) sa[mt] = (f32x4){0.f, 0.f, 0.f, 0.f};
    {
      bf16x8 qbh, qbl;
      unpack_pair(&Qs[(16 * w + lrow) * 36 + 8 * G], qbh, qbl);
#pragma unroll
      for (int mt = 0; mt < 4; ++mt) {
        bf16x8 kah, kal;
        unpack_pair(&Ks[(16 * mt + lrow) * 36 + 8 * G], kah, kal);
        sa[mt] = MFMA(kah, qbh, sa[mt], 0, 0, 0);
        sa[mt] = MFMA(kah, qbl, sa[mt], 0, 0, 0);
        sa[mt] = MFMA(kal, qbh, sa[mt], 0, 0, 0);
      }
    }
    // bias+mask (f32, pad = -1e9), register softmax over j (4 lanes x 16 regs)
    float pm[4][4];
    float mx = -3e38f;
    const float* bmr = bmF + (((size_t)(wi * NH + h) * 64) + 16 * w + lrow) * 64;
#pragma unroll
    for (int mt = 0; mt < 4; ++mt) {
      float4 bm4 = *(const float4*)(bmr + 16 * mt + 4 * G);
      pm[mt][0] = sa[mt][0] + bm4.x;
      pm[mt][1] = sa[mt][1] + bm4.y;
      pm[mt][2] = sa[mt][2] + bm4.z;
      pm[mt][3] = sa[mt][3] + bm4.w;
#pragma unroll
      for (int r = 0; r < 4; ++r) mx = fmaxf(mx, pm[mt][r]);
    }
    mx = fmaxf(mx, __shfl_xor(mx, 16));
    mx = fmaxf(mx, __shfl_xor(mx, 32));
    float sum = 0.f;
#pragma unroll
    for (int mt = 0; mt < 4; ++mt)
#pragma unroll
      for (int r = 0; r < 4; ++r) { pm[mt][r] = __expf(pm[mt][r] - mx); sum += pm[mt][r]; }
    sum += __shfl_xor(sum, 16);
    sum += __shfl_xor(sum, 32);
    float inv = 1.f / sum;
    // P (unnormalized) -> LDS, wave-local rows i = 16w+lrow
#pragma unroll
    for (int mt = 0; mt < 4; ++mt) {
      u32x4 pk;
#pragma unroll
      for (int r = 0; r < 4; ++r) pk[r] = packsplit(pm[mt][r]);
      *(u32x4*)&Ps[(16 * w + lrow) * 68 + 16 * mt + 4 * G] = pk;
    }
    // PV: out^T[d][i] = sum_j VT[d][j] P[i][j]
    f32x4 oa[2];
    oa[0] = (f32x4){0.f, 0.f, 0.f, 0.f};
    oa[1] = (f32x4){0.f, 0.f, 0.f, 0.f};
#pragma unroll
    for (int ks2 = 0; ks2 < 2; ++ks2) {
      bf16x8 pbh, pbl;
      unpack_pair(&Ps[(16 * w + lrow) * 68 + ks2 * 32 + 8 * G], pbh, pbl);
#pragma unroll
      for (int mtd = 0; mtd < 2; ++mtd) {
        bf16x8 vah, val_;
        unpack_pair(&VT[(16 * mtd + lrow) * 68 + ks2 * 32 + 8 * G], vah, val_);
        oa[mtd] = MFMA(vah, pbh, oa[mtd], 0, 0, 0);
        oa[mtd] = MFMA(vah, pbl, oa[mtd], 0, 0, 0);
        oa[mtd] = MFMA(val_, pbh, oa[mtd], 0, 0, 0);
      }
    }
    // attn-out -> AO[i][h*32 + d], normalized; wave-local rows
#pragma unroll
    for (int mtd = 0; mtd < 2; ++mtd) {
      u32x4 pk;
#pragma unroll
      for (int r = 0; r < 4; ++r) pk[r] = packsplit(oa[mtd][r] * inv);
      *(u32x4*)&AO[(16 * w + lrow) * 132 + 32 * h + 16 * mtd + 4 * G] = pk;
    }
    __syncthreads();
  }

  // ======== phase 3: proj  out = AO @ W2^T + b ========
  f32x4 pacc[8];
#pragma unroll
  for (int nt2 = 0; nt2 < 8; ++nt2) pacc[nt2] = (f32x4){0.f, 0.f, 0.f, 0.f};
#pragma unroll
  for (int ks = 0; ks < 4; ++ks) {
    bf16x8 aah, aal;
    unpack_pair(&AO[(16 * w + lrow) * 132 + ks * 32 + 8 * G], aah, aal);
#pragma unroll
    for (int nt2 = 0; nt2 < 8; ++nt2) {
      int wr = nt2 * 16 + lrow;
      bf16x8 bh = *(const bf16x8*)(pwh + (size_t)wr * DIMC + ks * 32 + 8 * G);
      bf16x8 bl = *(const bf16x8*)(pwl + (size_t)wr * DIMC + ks * 32 + 8 * G);
      pacc[nt2] = MFMA(aah, bh, pacc[nt2], 0, 0, 0);
      pacc[nt2] = MFMA(aah, bl, pacc[nt2], 0, 0, 0);
      pacc[nt2] = MFMA(aal, bh, pacc[nt2], 0, 0, 0);
    }
  }
#pragma unroll
  for (int nt2 = 0; nt2 < 8; ++nt2) {
    int cp = nt2 * 16 + lrow;
    float pb = proj_b[cp];
#pragma unroll
    for (int r = 0; r < 4; ++r) {
      int mrow = 16 * w + 4 * G + r;
      if (mrow < NTOK) out[((size_t)b * NTOK + mrow) * DIMC + cp] = pacc[nt2][r] + pb;
    }
  }
}

extern "C" void kernel_launch(void* const* d_in, const int* in_sizes, int n_in,
                              void* d_out, int out_size, void* d_ws, size_t ws_size,
                              hipStream_t stream) {
  const float* x          = (const float*)d_in[0];
  const float* mask       = (const float*)d_in[1];
  const float* qkv_w      = (const float*)d_in[2];
  const float* qkv_b      = (const float*)d_in[3];
  const float* proj_w     = (const float*)d_in[4];
  const float* proj_b     = (const float*)d_in[5];
  const float* bias_table = (const float*)d_in[6];
  const int*   rel_index  = (const int*)d_in[7];
  float* out = (float*)d_out;

  __bf16* wpack = (__bf16*)d_ws;
  const __bf16* qwh = wpack;
  const __bf16* qwl = wpack + 49152;
  const __bf16* pwh = wpack + 98304;
  const __bf16* pwl = wpack + 98304 + 16384;
  float* bmF = (float*)((char*)d_ws + 262144);   // 64*4*64*64 f32 = 4 MB

  wpack_k<<<dim3(256), 256, 0, stream>>>(qkv_w, proj_w, wpack);
  bmf_k<<<dim3(4096), 256, 0, stream>>>(mask, bias_table, rel_index, bmF);
  fused_k<<<dim3(B_ALL), 256, 0, stream>>>(x, qwh, qwl, qkv_b, pwh, pwl, proj_b, bmF, out);
}

// Round 13
// 707.371 us; speedup vs baseline: 1.0155x; 1.0155x over previous
//
#include <hip/hip_runtime.h>

#define B_ALL 4096
#define NWIN  64
#define NTOK  49
#define DIMC  128
#define NH    4
#define HD    32
#define SCALE 0.17677669529663687f  // 32^-0.5

typedef __attribute__((ext_vector_type(8))) __bf16 bf16x8;
typedef __attribute__((ext_vector_type(4))) float f32x4;
typedef __attribute__((ext_vector_type(4))) unsigned int u32x4;

#define MFMA __builtin_amdgcn_mfma_f32_16x16x32_bf16

// ws layout (bytes):
//   [0,       98304)   qw_hi (384*128 bf16) ; [98304,196608) qw_lo
//   [196608, 229376)   pw_hi (128*128 bf16) ; [229376,262144) pw_lo
//   [262144, 4456448)  bmF   (64*4*64*64 f32, [wi][h][i][j], pad = -1e9)

__global__ void wpack_k(const float* __restrict__ qkv_w, const float* __restrict__ proj_w,
                        __bf16* __restrict__ dst) {
  int idx = blockIdx.x * 256 + threadIdx.x;       // 65536 total
  float w;
  __bf16 *hi, *lo;
  if (idx < 49152) { w = qkv_w[idx]; hi = dst; lo = dst + 49152; }
  else { idx -= 49152; w = proj_w[idx]; hi = dst + 98304; lo = dst + 98304 + 16384; }
  __bf16 h = (__bf16)w;
  hi[idx] = h;
  lo[idx] = (__bf16)(w - (float)h);
}

__global__ void bmf_k(const float* __restrict__ mask, const float* __restrict__ bias_table,
                      const int* __restrict__ rel_index, float* __restrict__ bmF) {
  int idx = blockIdx.x * 256 + threadIdx.x;       // 64*4*64*64 = 1048576 (exact)
  int j  = idx & 63;
  int i  = (idx >> 6) & 63;
  int h  = (idx >> 12) & 3;
  int wi = idx >> 14;
  float v = -1e9f;
  if (i < NTOK && j < NTOK)
    v = bias_table[rel_index[i * NTOK + j] * NH + h] + mask[wi * (NTOK * NTOK) + i * NTOK + j];
  bmF[idx] = v;
}

__device__ __forceinline__ unsigned int packsplit(float f) {
  union { __bf16 b; unsigned short u; } H, L;
  H.b = (__bf16)f;
  L.b = (__bf16)(f - (float)H.b);
  return ((unsigned int)H.u << 16) | L.u;
}

__device__ __forceinline__ void unpack_pair(const unsigned int* sp, bf16x8& hi, bf16x8& lo) {
  union { u32x4 q[2]; unsigned int r[8]; } t;
  t.q[0] = *(const u32x4*)sp;
  t.q[1] = *(const u32x4*)(sp + 4);
  union { bf16x8 v; unsigned short u[8]; } H, L;
#pragma unroll
  for (int e = 0; e < 8; ++e) {
    H.u[e] = (unsigned short)(t.r[e] >> 16);
    L.u[e] = (unsigned short)(t.r[e] & 0xffffu);
  }
  hi = H.v; lo = L.v;
}

// One block per window. 4 waves. Wave w owns token-rows [16w,16w+16).
// LDS layout IDENTICAL to R7 (last passing fused kernel):
// Q[64][36] K[64][36] VT[32][68] P[64][68] AO[64][132] = 78336 B.
__global__ __launch_bounds__(256, 2)
void fused_k(const float* __restrict__ x,
             const __bf16* __restrict__ qwh, const __bf16* __restrict__ qwl,
             const float* __restrict__ qkv_b,
             const __bf16* __restrict__ pwh, const __bf16* __restrict__ pwl,
             const float* __restrict__ proj_b,
             const float* __restrict__ bmF, float* __restrict__ out) {
  __shared__ unsigned int smem[19584];
  unsigned int* Qs = smem;           // [64][36]
  unsigned int* Ks = smem + 2304;    // [64][36]
  unsigned int* VT = smem + 4608;    // [32][68]
  unsigned int* Ps = smem + 6784;    // [64][68]
  unsigned int* AO = smem + 11136;   // [64][132] (full size — no aliasing)

  const int tid  = threadIdx.x;
  const int lane = tid & 63, w = tid >> 6;
  const int lrow = lane & 15, G = lane >> 4;
  const int b = blockIdx.x, wi = b & (NWIN - 1);

  // ---- x A-frags: rows 16w+lrow, k = ks*32+8G..+8, hi/lo. Pad rows -> 0.
  bf16x8 xh[4], xl[4];
  {
    int row = 16 * w + lrow;
    const float* xr = x + ((size_t)b * NTOK + (row < NTOK ? row : 0)) * DIMC;
#pragma unroll
    for (int ks = 0; ks < 4; ++ks) {
      float4 a = *(const float4*)(xr + ks * 32 + 8 * G);
      float4 c = *(const float4*)(xr + ks * 32 + 8 * G + 4);
      float f[8] = {a.x, a.y, a.z, a.w, c.x, c.y, c.z, c.w};
      union { bf16x8 v; __bf16 e[8]; } H, L;
#pragma unroll
      for (int e2 = 0; e2 < 8; ++e2) {
        float fv = (row < NTOK) ? f[e2] : 0.f;
        __bf16 hh = (__bf16)fv;
        H.e[e2] = hh;
        L.e[e2] = (__bf16)(fv - (float)hh);
      }
      xh[ks] = H.v; xl[ks] = L.v;
    }
  }

#pragma unroll 1
  for (int h = 0; h < NH; ++h) {
    // ======== phase 1: C = x @ Wslice^T, head h — BATCHED register loads ========
    f32x4 acc[6];
#pragma unroll
    for (int nt = 0; nt < 6; ++nt) acc[nt] = (f32x4){0.f, 0.f, 0.f, 0.f};
#pragma unroll
    for (int ks = 0; ks < 4; ++ks) {
      bf16x8 wh_[6], wl_[6];          // 12 independent loads -> one latency event
#pragma unroll
      for (int nt = 0; nt < 6; ++nt) {
        int seg  = nt >> 1;
        int wrow = seg * 128 + h * 32 + (nt & 1) * 16 + lrow;
        wh_[nt] = *(const bf16x8*)(qwh + (size_t)wrow * DIMC + ks * 32 + 8 * G);
        wl_[nt] = *(const bf16x8*)(qwl + (size_t)wrow * DIMC + ks * 32 + 8 * G);
      }
#pragma unroll
      for (int nt = 0; nt < 6; ++nt) {
        acc[nt] = MFMA(xh[ks], wh_[nt], acc[nt], 0, 0, 0);
        acc[nt] = MFMA(xh[ks], wl_[nt], acc[nt], 0, 0, 0);
        acc[nt] = MFMA(xl[ks], wh_[nt], acc[nt], 0, 0, 0);
      }
    }
    // epilogue (identical to R7): C rows i = 16w+4G+r
#pragma unroll
    for (int nt = 0; nt < 6; ++nt) {
      int seg  = nt >> 1;
      int coln = seg * 128 + h * 32 + (nt & 1) * 16 + lrow;
      float bias = qkv_b[coln];
      if (seg == 0) {
#pragma unroll
        for (int r = 0; r < 4; ++r)
          Qs[(16 * w + 4 * G + r) * 36 + (nt & 1) * 16 + lrow] =
              packsplit((acc[nt][r] + bias) * SCALE);
      } else if (seg == 1) {
#pragma unroll
        for (int r = 0; r < 4; ++r)
          Ks[(16 * w + 4 * G + r) * 36 + (nt & 1) * 16 + lrow] =
              packsplit(acc[nt][r] + bias);
      } else {
        u32x4 pk;
#pragma unroll
        for (int r = 0; r < 4; ++r) pk[r] = packsplit(acc[nt][r] + bias);
        *(u32x4*)&VT[((nt & 1) * 16 + lrow) * 68 + 16 * w + 4 * G] = pk;
      }
    }
    __syncthreads();

    // ======== phase 2: attention head h (R7 math; bmF loads hoisted) ========
    const float* bmr = bmF + (((size_t)(wi * NH + h) * 64) + 16 * w + lrow) * 64;
    float4 bm4[4];
#pragma unroll
    for (int mt = 0; mt < 4; ++mt) bm4[mt] = *(const float4*)(bmr + 16 * mt + 4 * G);

    f32x4 sa[4];
#pragma unroll
    for (int mt = 0; mt < 4; ++mt) sa[mt] = (f32x4){0.f, 0.f, 0.f, 0.f};
    {
      bf16x8 qbh, qbl;
      unpack_pair(&Qs[(16 * w + lrow) * 36 + 8 * G], qbh, qbl);
#pragma unroll
      for (int mt = 0; mt < 4; ++mt) {
        bf16x8 kah, kal;
        unpack_pair(&Ks[(16 * mt + lrow) * 36 + 8 * G], kah, kal);
        sa[mt] = MFMA(kah, qbh, sa[mt], 0, 0, 0);
        sa[mt] = MFMA(kah, qbl, sa[mt], 0, 0, 0);
        sa[mt] = MFMA(kal, qbh, sa[mt], 0, 0, 0);
      }
    }
    float pm[4][4];
    float mx = -3e38f;
#pragma unroll
    for (int mt = 0; mt < 4; ++mt) {
      pm[mt][0] = sa[mt][0] + bm4[mt].x;
      pm[mt][1] = sa[mt][1] + bm4[mt].y;
      pm[mt][2] = sa[mt][2] + bm4[mt].z;
      pm[mt][3] = sa[mt][3] + bm4[mt].w;
#pragma unroll
      for (int r = 0; r < 4; ++r) mx = fmaxf(mx, pm[mt][r]);
    }
    mx = fmaxf(mx, __shfl_xor(mx, 16));
    mx = fmaxf(mx, __shfl_xor(mx, 32));
    float sum = 0.f;
#pragma unroll
    for (int mt = 0; mt < 4; ++mt)
#pragma unroll
      for (int r = 0; r < 4; ++r) { pm[mt][r] = __expf(pm[mt][r] - mx); sum += pm[mt][r]; }
    sum += __shfl_xor(sum, 16);
    sum += __shfl_xor(sum, 32);
    float inv = 1.f / sum;
#pragma unroll
    for (int mt = 0; mt < 4; ++mt) {
      u32x4 pk;
#pragma unroll
      for (int r = 0; r < 4; ++r) pk[r] = packsplit(pm[mt][r]);
      *(u32x4*)&Ps[(16 * w + lrow) * 68 + 16 * mt + 4 * G] = pk;
    }
    f32x4 oa[2];
    oa[0] = (f32x4){0.f, 0.f, 0.f, 0.f};
    oa[1] = (f32x4){0.f, 0.f, 0.f, 0.f};
#pragma unroll
    for (int ks2 = 0; ks2 < 2; ++ks2) {
      bf16x8 pbh, pbl;
      unpack_pair(&Ps[(16 * w + lrow) * 68 + ks2 * 32 + 8 * G], pbh, pbl);
#pragma unroll
      for (int mtd = 0; mtd < 2; ++mtd) {
        bf16x8 vah, val_;
        unpack_pair(&VT[(16 * mtd + lrow) * 68 + ks2 * 32 + 8 * G], vah, val_);
        oa[mtd] = MFMA(vah, pbh, oa[mtd], 0, 0, 0);
        oa[mtd] = MFMA(vah, pbl, oa[mtd], 0, 0, 0);
        oa[mtd] = MFMA(val_, pbh, oa[mtd], 0, 0, 0);
      }
    }
#pragma unroll
    for (int mtd = 0; mtd < 2; ++mtd) {
      u32x4 pk;
#pragma unroll
      for (int r = 0; r < 4; ++r) pk[r] = packsplit(oa[mtd][r] * inv);
      *(u32x4*)&AO[(16 * w + lrow) * 132 + 32 * h + 16 * mtd + 4 * G] = pk;
    }
    __syncthreads();
  }

  // ======== phase 3: proj — BATCHED register loads per ks ========
  f32x4 pacc[8];
#pragma unroll
  for (int nt2 = 0; nt2 < 8; ++nt2) pacc[nt2] = (f32x4){0.f, 0.f, 0.f, 0.f};
#pragma unroll
  for (int ks = 0; ks < 4; ++ks) {
    bf16x8 ph_[8], pl_[8];            // 16 independent loads -> one latency event
#pragma unroll
    for (int nt2 = 0; nt2 < 8; ++nt2) {
      int wr = nt2 * 16 + lrow;
      ph_[nt2] = *(const bf16x8*)(pwh + (size_t)wr * DIMC + ks * 32 + 8 * G);
      pl_[nt2] = *(const bf16x8*)(pwl + (size_t)wr * DIMC + ks * 32 + 8 * G);
    }
    bf16x8 aah, aal;
    unpack_pair(&AO[(16 * w + lrow) * 132 + ks * 32 + 8 * G], aah, aal);
#pragma unroll
    for (int nt2 = 0; nt2 < 8; ++nt2) {
      pacc[nt2] = MFMA(aah, ph_[nt2], pacc[nt2], 0, 0, 0);
      pacc[nt2] = MFMA(aah, pl_[nt2], pacc[nt2], 0, 0, 0);
      pacc[nt2] = MFMA(aal, ph_[nt2], pacc[nt2], 0, 0, 0);
    }
  }
#pragma unroll
  for (int nt2 = 0; nt2 < 8; ++nt2) {
    int cp = nt2 * 16 + lrow;
    float pb = proj_b[cp];
#pragma unroll
    for (int r = 0; r < 4; ++r) {
      int mrow = 16 * w + 4 * G + r;
      if (mrow < NTOK) out[((size_t)b * NTOK + mrow) * DIMC + cp] = pacc[nt2][r] + pb;
    }
  }
}

extern "C" void kernel_launch(void* const* d_in, const int* in_sizes, int n_in,
                              void* d_out, int out_size, void* d_ws, size_t ws_size,
                              hipStream_t stream) {
  const float* x          = (const float*)d_in[0];
  const float* mask       = (const float*)d_in[1];
  const float* qkv_w      = (const float*)d_in[2];
  const float* qkv_b      = (const float*)d_in[3];
  const float* proj_w     = (const float*)d_in[4];
  const float* proj_b     = (const float*)d_in[5];
  const float* bias_table = (const float*)d_in[6];
  const int*   rel_index  = (const int*)d_in[7];
  float* out = (float*)d_out;

  __bf16* wpack = (__bf16*)d_ws;
  const __bf16* qwh = wpack;
  const __bf16* qwl = wpack + 49152;
  const __bf16* pwh = wpack + 98304;
  const __bf16* pwl = wpack + 98304 + 16384;
  float* bmF = (float*)((char*)d_ws + 262144);   // 4 MB

  wpack_k<<<dim3(256), 256, 0, stream>>>(qkv_w, proj_w, wpack);
  bmf_k<<<dim3(4096), 256, 0, stream>>>(mask, bias_table, rel_index, bmF);
  fused_k<<<dim3(B_ALL), 256, 0, stream>>>(x, qwh, qwl, qkv_b, pwh, pwl, proj_b, bmF, out);
}